// Round 3
// baseline (315.054 us; speedup 1.0000x reference)
//
#include <hip/hip_runtime.h>
#include <stdint.h>

#define B_DIM 4
#define L_DIM 512
#define D_DIM 768
#define S_DIM 4096
#define DFF_DIM 3072
#define M_DIM (B_DIM * S_DIM)   // 16384

typedef unsigned short ushort_t;
typedef __attribute__((ext_vector_type(8))) short short8;
typedef __attribute__((ext_vector_type(4))) float floatx4;

// round-to-nearest-even fp32 -> bf16 bits
__device__ __forceinline__ ushort_t f2bf(float x) {
  unsigned int u = __float_as_uint(x);
  u += 0x7FFFu + ((u >> 16) & 1u);
  return (ushort_t)(u >> 16);
}

// async 16B global->LDS (wave-uniform base + lane*16 layout required)
__device__ __forceinline__ void load_lds16(const ushort_t* g, ushort_t* lds) {
  __builtin_amdgcn_global_load_lds(
      (const __attribute__((address_space(1))) unsigned int*)g,
      (__attribute__((address_space(3))) unsigned int*)lds, 16, 0, 0);
}

// ---------------------------------------------------------------------------
// Transpose + downcast: in is K x N fp32 row-major, out is N x K bf16 row-major
// ---------------------------------------------------------------------------
__global__ __launch_bounds__(256)
void transpose_bf16(const float* __restrict__ in, ushort_t* __restrict__ out,
                    int K, int N) {
  __shared__ float tile[32][33];
  const int k0 = blockIdx.x * 32;
  const int n0 = blockIdx.y * 32;
  const int tx = threadIdx.x & 31;
  const int ty = threadIdx.x >> 5;  // 0..7
#pragma unroll
  for (int r = 0; r < 32; r += 8)
    tile[ty + r][tx] = in[(long)(k0 + ty + r) * N + n0 + tx];
  __syncthreads();
#pragma unroll
  for (int r = 0; r < 32; r += 8)
    out[(long)(n0 + ty + r) * K + k0 + tx] = f2bf(tile[tx][ty + r]);
}

// ---------------------------------------------------------------------------
// Span gather + mean: one WAVE per span (4096 blocks x 4 waves).
// Each lane owns 12 columns (768 = 64 lanes * 12).
// ---------------------------------------------------------------------------
__global__ __launch_bounds__(256)
void span_reps(const float* __restrict__ h, const int* __restrict__ span_idx,
               ushort_t* __restrict__ A) {
  const int wave = threadIdx.x >> 6;
  const int lane = threadIdx.x & 63;
  const int span = blockIdx.x * 4 + wave;  // 0..M-1
  const int b = span >> 12;                // span / S_DIM
  const int start = span_idx[span * 2 + 0];
  const int end   = span_idx[span * 2 + 1];
  const float inv = 1.0f / (float)(end - start + 1);
  const float* hb = h + ((long)b * L_DIM + start) * D_DIM + lane;
  float a[12];
#pragma unroll
  for (int c = 0; c < 12; ++c) a[c] = 0.0f;
  for (int p = start; p <= end; ++p) {
#pragma unroll
    for (int c = 0; c < 12; ++c) a[c] += hb[c * 64];
    hb += D_DIM;
  }
  ushort_t* o = A + (long)span * D_DIM + lane;
#pragma unroll
  for (int c = 0; c < 12; ++c) o[c * 64] = f2bf(a[c] * inv);
}

// ---------------------------------------------------------------------------
// bf16 GEMM: C[M][N] = A[M][K] * Bt[N][K]^T (+bias epilogue)
// 128x128 tile, BK=32, double-buffered LDS, prefetch-ahead, ONE barrier/iter.
// Iteration k: barrier (drains prefetch issued last iter) -> issue prefetch
// k+1 into other buffer -> compute from buffer k. HBM staging latency is
// hidden behind the previous iteration's compute instead of being exposed
// at the barrier.
// Grid is (N/128, M/128): blocks sharing an A-panel are launch-adjacent
// (L2 reuse of the once-read A operand).
// MODE 0: out = relu(acc + bias[col]) -> bf16   (GEMM1 -> Hmid)
// MODE 1: out = acc + bias[col]       -> fp32   (GEMM2 -> final)
// ---------------------------------------------------------------------------
template <int MODE>
__global__ __launch_bounds__(256)
void gemm_bt(const ushort_t* __restrict__ A, const ushort_t* __restrict__ Bt,
             const float* __restrict__ bias, void* __restrict__ Cv,
             int M, int N, int K) {
  __shared__ ushort_t As[2][128 * 32];
  __shared__ ushort_t Bs[2][128 * 32];

  const int tid  = threadIdx.x;
  const int lane = tid & 63;
  const int wave = tid >> 6;
  const int l16  = lane & 15;
  const int quad = lane >> 4;

  const int bn = blockIdx.x;
  const int bm = blockIdx.y;

  const int wm = (wave & 1) * 64;
  const int wn = (wave >> 1) * 64;

  floatx4 acc[4][4];
#pragma unroll
  for (int i = 0; i < 4; ++i)
#pragma unroll
    for (int j = 0; j < 4; ++j)
      acc[i][j] = (floatx4)0.0f;

  // staging: 512 16B segments per tile; seg s -> row = s>>2, kchunk = (s&3)*8
  const int s0 = tid, s1 = tid + 256;
  const ushort_t* gA0 = A + (long)(bm * 128 + (s0 >> 2)) * K + (s0 & 3) * 8;
  const ushort_t* gA1 = A + (long)(bm * 128 + (s1 >> 2)) * K + (s1 & 3) * 8;
  const ushort_t* gB0 = Bt + (long)(bn * 128 + (s0 >> 2)) * K + (s0 & 3) * 8;
  const ushort_t* gB1 = Bt + (long)(bn * 128 + (s1 >> 2)) * K + (s1 & 3) * 8;

  const int nk = K >> 5;  // K/32 iterations

  // prologue: prefetch tile 0 into buffer 0
  load_lds16(gA0, &As[0][0] + s0 * 8);
  load_lds16(gA1, &As[0][0] + s1 * 8);
  load_lds16(gB0, &Bs[0][0] + s0 * 8);
  load_lds16(gB1, &Bs[0][0] + s1 * 8);

  for (int k = 0; k < nk; ++k) {
    const int cur = k & 1;
    const int nxt = cur ^ 1;
    __syncthreads();  // drains vmcnt: tile k (prefetched one iter ago) ready

    if (k + 1 < nk) {  // prefetch tile k+1 into the other buffer
      const int off = (k + 1) * 32;
      load_lds16(gA0 + off, &As[nxt][0] + s0 * 8);
      load_lds16(gA1 + off, &As[nxt][0] + s1 * 8);
      load_lds16(gB0 + off, &Bs[nxt][0] + s0 * 8);
      load_lds16(gB1 + off, &Bs[nxt][0] + s1 * 8);
    }

    short8 af[4], bf[4];
#pragma unroll
    for (int i = 0; i < 4; ++i)
      af[i] = *(const short8*)(&As[cur][0] + (wm + i * 16 + l16) * 32 + quad * 8);
#pragma unroll
    for (int j = 0; j < 4; ++j)
      bf[j] = *(const short8*)(&Bs[cur][0] + (wn + j * 16 + l16) * 32 + quad * 8);
#pragma unroll
    for (int i = 0; i < 4; ++i)
#pragma unroll
      for (int j = 0; j < 4; ++j)
        acc[i][j] = __builtin_amdgcn_mfma_f32_16x16x32_bf16(af[i], bf[j], acc[i][j], 0, 0, 0);
  }

  // epilogue: C/D layout col = lane&15, row = quad*4 + r
#pragma unroll
  for (int i = 0; i < 4; ++i) {
#pragma unroll
    for (int j = 0; j < 4; ++j) {
      const int col = bn * 128 + wn + j * 16 + l16;
      const float bv = bias[col];
      const int row0 = bm * 128 + wm + i * 16 + quad * 4;
#pragma unroll
      for (int r = 0; r < 4; ++r) {
        float v = acc[i][j][r] + bv;
        if (MODE == 0) {
          v = v > 0.0f ? v : 0.0f;
          ((ushort_t*)Cv)[(long)(row0 + r) * N + col] = f2bf(v);
        } else {
          ((float*)Cv)[(long)(row0 + r) * N + col] = v;
        }
      }
    }
  }
}

extern "C" void kernel_launch(void* const* d_in, const int* in_sizes, int n_in,
                              void* d_out, int out_size, void* d_ws, size_t ws_size,
                              hipStream_t stream) {
  const float* h        = (const float*)d_in[0];
  const int*   span_idx = (const int*)d_in[1];
  const float* W1       = (const float*)d_in[2];
  const float* b1       = (const float*)d_in[3];
  const float* W2       = (const float*)d_in[4];
  const float* b2       = (const float*)d_in[5];
  float* out = (float*)d_out;

  // workspace layout (bf16 elements): A | W1T | W2T | Hmid
  ushort_t* A   = (ushort_t*)d_ws;
  ushort_t* W1T = A + (size_t)M_DIM * D_DIM;
  ushort_t* W2T = W1T + (size_t)DFF_DIM * D_DIM;
  ushort_t* Hm  = W2T + (size_t)D_DIM * DFF_DIM;

  transpose_bf16<<<dim3(D_DIM / 32, DFF_DIM / 32), 256, 0, stream>>>(W1, W1T, D_DIM, DFF_DIM);
  transpose_bf16<<<dim3(DFF_DIM / 32, D_DIM / 32), 256, 0, stream>>>(W2, W2T, DFF_DIM, D_DIM);

  span_reps<<<M_DIM / 4, 256, 0, stream>>>(h, span_idx, A);

  // GEMM1: A (M x D) * W1 (D x DFF) + b1, relu -> Hmid bf16 (M x DFF)
  gemm_bt<0><<<dim3(DFF_DIM / 128, M_DIM / 128), 256, 0, stream>>>(
      A, W1T, b1, Hm, M_DIM, DFF_DIM, D_DIM);

  // GEMM2: Hmid (M x DFF) * W2 (DFF x D) + b2 -> out fp32 (M x D)
  gemm_bt<1><<<dim3(D_DIM / 128, M_DIM / 128), 256, 0, stream>>>(
      Hm, W2T, b2, out, M_DIM, D_DIM, DFF_DIM);
}

// Round 4
// 279.202 us; speedup vs baseline: 1.1284x; 1.1284x over previous
//
#include <hip/hip_runtime.h>
#include <stdint.h>

#define B_DIM 4
#define L_DIM 512
#define D_DIM 768
#define S_DIM 4096
#define DFF_DIM 3072
#define M_DIM (B_DIM * S_DIM)   // 16384

typedef unsigned short ushort_t;
typedef __attribute__((ext_vector_type(8))) short short8;
typedef __attribute__((ext_vector_type(4))) float floatx4;

// round-to-nearest-even fp32 -> bf16 bits
__device__ __forceinline__ ushort_t f2bf(float x) {
  unsigned int u = __float_as_uint(x);
  u += 0x7FFFu + ((u >> 16) & 1u);
  return (ushort_t)(u >> 16);
}

// async 16B global->LDS (wave-uniform base + lane*16 layout required)
__device__ __forceinline__ void load_lds16(const ushort_t* g, ushort_t* lds) {
  __builtin_amdgcn_global_load_lds(
      (const __attribute__((address_space(1))) unsigned int*)g,
      (__attribute__((address_space(3))) unsigned int*)lds, 16, 0, 0);
}

// ---------------------------------------------------------------------------
// Fused prep: W1 transpose | W2 transpose | span gather+mean, one launch.
// blocks [0,2304): W1 (768x3072 fp32) -> W1T (3072x768 bf16)
// blocks [2304,4608): W2 (3072x768 fp32) -> W2T (768x3072 bf16)
// blocks [4608,8704): span_reps, 4 spans/block (wave per span)
// ---------------------------------------------------------------------------
__device__ __forceinline__ void transpose_body(const float* __restrict__ in,
                                               ushort_t* __restrict__ out,
                                               int K, int N, int kb, int nb) {
  __shared__ float tile[32][33];
  const int k0 = kb * 32;
  const int n0 = nb * 32;
  const int tx = threadIdx.x & 31;
  const int ty = threadIdx.x >> 5;  // 0..7
#pragma unroll
  for (int r = 0; r < 32; r += 8)
    tile[ty + r][tx] = in[(long)(k0 + ty + r) * N + n0 + tx];
  __syncthreads();
#pragma unroll
  for (int r = 0; r < 32; r += 8)
    out[(long)(n0 + ty + r) * K + k0 + tx] = f2bf(tile[tx][ty + r]);
}

__device__ __forceinline__ void span_body(const float* __restrict__ h,
                                          const int* __restrict__ span_idx,
                                          ushort_t* __restrict__ A, int blk) {
  const int wave = threadIdx.x >> 6;
  const int lane = threadIdx.x & 63;
  const int span = blk * 4 + wave;  // 0..M-1
  const int b = span >> 12;         // span / S_DIM
  const int start = span_idx[span * 2 + 0];
  const int end   = span_idx[span * 2 + 1];
  const float inv = 1.0f / (float)(end - start + 1);
  const float* hb = h + ((long)b * L_DIM + start) * D_DIM + lane;
  float a[12];
#pragma unroll
  for (int c = 0; c < 12; ++c) a[c] = 0.0f;
  for (int p = start; p <= end; ++p) {
#pragma unroll
    for (int c = 0; c < 12; ++c) a[c] += hb[c * 64];
    hb += D_DIM;
  }
  ushort_t* o = A + (long)span * D_DIM + lane;
#pragma unroll
  for (int c = 0; c < 12; ++c) o[c * 64] = f2bf(a[c] * inv);
}

__global__ __launch_bounds__(256)
void prep(const float* __restrict__ W1, ushort_t* __restrict__ W1T,
          const float* __restrict__ W2, ushort_t* __restrict__ W2T,
          const float* __restrict__ h, const int* __restrict__ span_idx,
          ushort_t* __restrict__ A) {
  const int blk = blockIdx.x;
  if (blk < 2304) {
    transpose_body(W1, W1T, D_DIM, DFF_DIM, blk % 24, blk / 24);
  } else if (blk < 4608) {
    const int b = blk - 2304;
    transpose_body(W2, W2T, DFF_DIM, D_DIM, b % 96, b / 96);
  } else {
    span_body(h, span_idx, A, blk - 4608);
  }
}

// ---------------------------------------------------------------------------
// bf16 GEMM: C[M][N] = A[M][K] * Bt[N][K]^T (+bias epilogue)
// 128x128 tile, BK=32, double-buffered LDS, one barrier/iter, and a
// chunk-XOR LDS swizzle: LDS[r][c'] holds global k-chunk c' ^ (r&3) ^ ((r>>2)&3).
// This breaks the 8-way bank aliasing of the fragment ds_read_b128 pattern
// (rows r, r+2 alias at 64-B row stride) down to 2-way (free). The swizzle is
// applied on the GLOBAL source address during staging, so the
// global_load_lds lane-contiguous LDS destination rule is preserved.
// MODE 0: out = relu(acc + bias[col]) -> bf16   (GEMM1 -> Hmid)
// MODE 1: out = acc + bias[col]       -> fp32   (GEMM2 -> final)
// ---------------------------------------------------------------------------
template <int MODE>
__global__ __launch_bounds__(256)
void gemm_bt(const ushort_t* __restrict__ A, const ushort_t* __restrict__ Bt,
             const float* __restrict__ bias, void* __restrict__ Cv,
             int M, int N, int K) {
  __shared__ ushort_t As[2][128 * 32];
  __shared__ ushort_t Bs[2][128 * 32];

  const int tid  = threadIdx.x;
  const int lane = tid & 63;
  const int wave = tid >> 6;
  const int l16  = lane & 15;
  const int quad = lane >> 4;

  const int bm = blockIdx.x;
  const int bn = blockIdx.y;

  const int wm = (wave & 1) * 64;
  const int wn = (wave >> 1) * 64;

  // fragment-read chunk swizzle: row = wm+i*16+l16; swz(row) depends only on l16
  const int swz  = (l16 & 3) ^ ((l16 >> 2) & 3);
  const int coff = (quad ^ swz) * 8;  // element offset of this lane's 16-B chunk

  floatx4 acc[4][4];
#pragma unroll
  for (int i = 0; i < 4; ++i)
#pragma unroll
    for (int j = 0; j < 4; ++j)
      acc[i][j] = (floatx4)0.0f;

  // staging: 512 16-B segments/tile; seg s -> LDS row s>>2, LDS chunk s&3,
  // global chunk = (s&3) ^ swz(row)
  const int s0 = tid, s1 = tid + 256;
  const int r0 = s0 >> 2, r1 = s1 >> 2;
  const int c0 = (s0 & 3) ^ (r0 & 3) ^ ((r0 >> 2) & 3);
  const int c1 = (s1 & 3) ^ (r1 & 3) ^ ((r1 >> 2) & 3);
  const ushort_t* gA0 = A + (long)(bm * 128 + r0) * K + c0 * 8;
  const ushort_t* gA1 = A + (long)(bm * 128 + r1) * K + c1 * 8;
  const ushort_t* gB0 = Bt + (long)(bn * 128 + r0) * K + c0 * 8;
  const ushort_t* gB1 = Bt + (long)(bn * 128 + r1) * K + c1 * 8;

  const int nk = K >> 5;  // K/32 iterations

  // prologue: prefetch tile 0 into buffer 0
  load_lds16(gA0, &As[0][0] + s0 * 8);
  load_lds16(gA1, &As[0][0] + s1 * 8);
  load_lds16(gB0, &Bs[0][0] + s0 * 8);
  load_lds16(gB1, &Bs[0][0] + s1 * 8);

  for (int k = 0; k < nk; ++k) {
    const int cur = k & 1;
    const int nxt = cur ^ 1;
    __syncthreads();  // drains vmcnt: tile k (prefetched one iter ago) ready

    if (k + 1 < nk) {  // prefetch tile k+1 into the other buffer
      const int off = (k + 1) * 32;
      load_lds16(gA0 + off, &As[nxt][0] + s0 * 8);
      load_lds16(gA1 + off, &As[nxt][0] + s1 * 8);
      load_lds16(gB0 + off, &Bs[nxt][0] + s0 * 8);
      load_lds16(gB1 + off, &Bs[nxt][0] + s1 * 8);
    }

    short8 af[4], bf[4];
#pragma unroll
    for (int i = 0; i < 4; ++i)
      af[i] = *(const short8*)(&As[cur][0] + (wm + i * 16 + l16) * 32 + coff);
#pragma unroll
    for (int j = 0; j < 4; ++j)
      bf[j] = *(const short8*)(&Bs[cur][0] + (wn + j * 16 + l16) * 32 + coff);
#pragma unroll
    for (int i = 0; i < 4; ++i)
#pragma unroll
      for (int j = 0; j < 4; ++j)
        acc[i][j] = __builtin_amdgcn_mfma_f32_16x16x32_bf16(af[i], bf[j], acc[i][j], 0, 0, 0);
  }

  // epilogue: C/D layout col = lane&15, row = quad*4 + r
#pragma unroll
  for (int i = 0; i < 4; ++i) {
#pragma unroll
    for (int j = 0; j < 4; ++j) {
      const int col = bn * 128 + wn + j * 16 + l16;
      const float bv = bias[col];
      const int row0 = bm * 128 + wm + i * 16 + quad * 4;
#pragma unroll
      for (int r = 0; r < 4; ++r) {
        float v = acc[i][j][r] + bv;
        if (MODE == 0) {
          v = v > 0.0f ? v : 0.0f;
          ((ushort_t*)Cv)[(long)(row0 + r) * N + col] = f2bf(v);
        } else {
          ((float*)Cv)[(long)(row0 + r) * N + col] = v;
        }
      }
    }
  }
}

extern "C" void kernel_launch(void* const* d_in, const int* in_sizes, int n_in,
                              void* d_out, int out_size, void* d_ws, size_t ws_size,
                              hipStream_t stream) {
  const float* h        = (const float*)d_in[0];
  const int*   span_idx = (const int*)d_in[1];
  const float* W1       = (const float*)d_in[2];
  const float* b1       = (const float*)d_in[3];
  const float* W2       = (const float*)d_in[4];
  const float* b2       = (const float*)d_in[5];
  float* out = (float*)d_out;

  // workspace layout (bf16 elements): A | W1T | W2T | Hmid
  ushort_t* A   = (ushort_t*)d_ws;
  ushort_t* W1T = A + (size_t)M_DIM * D_DIM;
  ushort_t* W2T = W1T + (size_t)DFF_DIM * D_DIM;
  ushort_t* Hm  = W2T + (size_t)D_DIM * DFF_DIM;

  // fused prep: both weight transposes + span gather in one launch
  prep<<<2304 + 2304 + M_DIM / 4, 256, 0, stream>>>(W1, W1T, W2, W2T, h, span_idx, A);

  // GEMM1: A (M x D) * W1 (D x DFF) + b1, relu -> Hmid bf16 (M x DFF)
  // grid bm-fast: consecutive blocks share the B-tile, A streamed once (low FETCH)
  gemm_bt<0><<<dim3(M_DIM / 128, DFF_DIM / 128), 256, 0, stream>>>(
      A, W1T, b1, Hm, M_DIM, DFF_DIM, D_DIM);

  // GEMM2: Hmid (M x DFF) * W2 (DFF x D) + b2 -> out fp32 (M x D)
  gemm_bt<1><<<dim3(M_DIM / 128, D_DIM / 128), 256, 0, stream>>>(
      Hm, W2T, b2, out, M_DIM, D_DIM, DFF_DIM);
}